// Round 6
// baseline (625.797 us; speedup 1.0000x reference)
//
#include <hip/hip_runtime.h>
#include <hip/hip_bf16.h>

// Bahdanau attention, MI355X. B=32, T=2048, D=1024, U=1024.
// R9: score GEMM — B streamed from L2 to registers (no LDS), A via glls16
// 3-buffer + asm ds_read.
// R8 post-mortem: plain ds_reads aliasing glls16 dests make LLVM insert its
// own vmcnt(0) before every ds_read batch -> pipeline drained every step (my
// counted vmcnt(3) was downstream of it). Also LDS read traffic (A+B frags,
// 64KB/block-step) was co-dominant with MFMA. Fixes:
//  - W1T re-laid out fragment-tiled: idx = ((u>>4)*32 + (d>>5))*512 +
//    ((u&15)*4 + ((d>>3)&3))*8 + (d&7). B frag = ONE coalesced
//    global_load_dwordx4 per lane from L2-resident 2MB array. LDS = A only.
//  - A: glls16 3-buf (3x8KB), asm ds_read_b128 + lgkmcnt(0) + sched_barrier
//    (rule 18), raw s_barrier. NO explicit vmcnt: per-step issue order
//    [B(t) loads, sched_barrier, glls16 A(t+2), ds_reads]; compiler's
//    in-order counted wait for B(t) retires A(t+1) and keeps A(t+2) flying.
//  - VGPR ~111 (af16+bf16+acc64+addr) -> 2 blocks/CU at (512,4); 24KB LDS.

typedef __bf16 bf16x8 __attribute__((ext_vector_type(8)));
typedef __bf16 bf16x4 __attribute__((ext_vector_type(4)));
typedef short  s16x8  __attribute__((ext_vector_type(8)));
typedef float  f32x4  __attribute__((ext_vector_type(4)));

#define B_  32
#define T_  2048
#define D_  1024
#define U_  1024
#define BT_ (B_*T_)

// ws layout (bytes)
#define WS_W1T    ((size_t)0)                          // 2 MiB bf16 (tiled or row)
#define WS_PROJQ  ((size_t)(2u*1024*1024))             // 128 KiB fp32 [B][U]
#define WS_SCORE  ((size_t)(2u*1024*1024 + 128u*1024)) // 256 KiB fp32 [B*T]
#define WS_VALB   ((size_t)(4u*1024*1024))             // 128 MiB bf16 [BT][D]
#define WS_NEEDED (WS_VALB + (size_t)BT_ * D_ * 2)

__device__ __forceinline__ float tanh_fast(float x) {
    const float e = __expf(2.0f * x);
    return 1.0f - __fdividef(2.0f, e + 1.0f);
}

__device__ __forceinline__ void glls16(const void* g, void* l) {
    __builtin_amdgcn_global_load_lds(
        (const __attribute__((address_space(1))) void*)g,
        (__attribute__((address_space(3))) void*)l, 16, 0, 0);
}

// ---------------- init: projq = b1+b2 (broadcast), score = 0 ----------------
__global__ void init_kernel(const float* __restrict__ b1, const float* __restrict__ b2,
                            float* __restrict__ projq, float* __restrict__ score) {
    int i = blockIdx.x * 256 + threadIdx.x;       // grid 384*256 = 98304 exact
    if (i < B_ * U_) {
        projq[i] = b1[i & (U_ - 1)] + b2[i & (U_ - 1)];
    } else {
        score[i - B_ * U_] = 0.0f;
    }
}

// ---------------- values fp32 -> bf16 (streaming) ----------------
__global__ void convert_kernel(const float* __restrict__ v, __bf16* __restrict__ o) {
    const size_t i = ((size_t)blockIdx.x * 256 + threadIdx.x) * 8;   // grid 32768
    const float4 a = *(const float4*)(v + i);
    const float4 b = *(const float4*)(v + i + 4);
    bf16x8 h;
    h[0] = (__bf16)a.x; h[1] = (__bf16)a.y; h[2] = (__bf16)a.z; h[3] = (__bf16)a.w;
    h[4] = (__bf16)b.x; h[5] = (__bf16)b.y; h[6] = (__bf16)b.z; h[7] = (__bf16)b.w;
    *(bf16x8*)(o + i) = h;
}

// ---- W1 [D][U] fp32 -> fragment-tiled bf16 (main path) ----
// idx(u,d) = ((u>>4)*32 + (d>>5))*512 + ((u&15)*4 + ((d>>3)&3))*8 + (d&7)
__global__ void w1_transpose_tiled_kernel(const float* __restrict__ W1, __bf16* __restrict__ W1TT) {
    __shared__ float tile[64][65];
    const int bx = blockIdx.x & 15;   // u tile
    const int by = blockIdx.x >> 4;   // d tile
    const int tid = threadIdx.x;      // 256
    const int j  = tid & 63;
    const int i0 = tid >> 6;          // 0..3
#pragma unroll
    for (int p = 0; p < 16; ++p) {
        const int i = i0 + p * 4;
        tile[i][j] = W1[(size_t)(by * 64 + i) * U_ + bx * 64 + j];
    }
    __syncthreads();
#pragma unroll
    for (int p = 0; p < 16; ++p) {
        const int i = i0 + p * 4;     // local u row
        const int u = bx * 64 + i;
        const int d = by * 64 + j;
        const int idx = (((u >> 4) * 32 + (d >> 5)) * 512) +
                        ((u & 15) * 4 + ((d >> 3) & 3)) * 8 + (d & 7);
        W1TT[idx] = (__bf16)tile[j][i];
    }
}

// ---- W1 [D][U] fp32 -> row-major W1T [U][D] bf16 (fallback path) ----
__global__ void w1_transpose_kernel(const float* __restrict__ W1, __bf16* __restrict__ W1T) {
    __shared__ float tile[64][65];
    const int bx = blockIdx.x & 15;   // u tile
    const int by = blockIdx.x >> 4;   // d tile
    const int tid = threadIdx.x;      // 256
    const int j  = tid & 63;
    const int i0 = tid >> 6;          // 0..3
#pragma unroll
    for (int p = 0; p < 16; ++p) {
        const int i = i0 + p * 4;
        tile[i][j] = W1[(size_t)(by * 64 + i) * U_ + bx * 64 + j];
    }
    __syncthreads();
#pragma unroll
    for (int p = 0; p < 16; ++p) {
        const int i = i0 + p * 4;     // local u row
        W1T[(size_t)(bx * 64 + i) * D_ + by * 64 + j] = (__bf16)tile[j][i];
    }
}

// ---------------- projq += query @ W2 (fp32, d-split + atomics) ----------------
__global__ void projq_kernel(const float* __restrict__ query, const float* __restrict__ W2,
                             float* __restrict__ projq) {
    __shared__ float q[128];
    const int b  = blockIdx.x >> 3;   // 32
    const int dc = blockIdx.x & 7;    // 8 chunks of 128 d
    const int tid = threadIdx.x;      // 256
    if (tid < 128) q[tid] = query[(size_t)b * D_ + dc * 128 + tid];
    __syncthreads();
    const int u0 = tid * 4;
    float a0 = 0.f, a1 = 0.f, a2 = 0.f, a3 = 0.f;
    for (int d = 0; d < 128; ++d) {
        const float4 w = *(const float4*)(W2 + (size_t)(dc * 128 + d) * U_ + u0);
        const float qd = q[d];
        a0 = fmaf(qd, w.x, a0); a1 = fmaf(qd, w.y, a1);
        a2 = fmaf(qd, w.z, a2); a3 = fmaf(qd, w.w, a3);
    }
    float* p = projq + (size_t)b * U_ + u0;
    atomicAdd(p + 0, a0); atomicAdd(p + 1, a1);
    atomicAdd(p + 2, a2); atomicAdd(p + 3, a3);
}

// ---------------- fused score GEMM: A-LDS / B-from-L2 ----------------
// Grid 2048 = 512 mblk x 4 nblk, XCD-swizzled. 512 threads = 8 waves (2M x 4N),
// wave tile 64x64, acc[4][4]. LDS: 3 x A[128][32] bf16 = 24 KiB (swizzled as
// R7/R8: phys slot = log ^ ((row>>1)&3)). B frags loaded per step directly
// from fragment-tiled W1TT (L2-resident) — one dwordx4 per lane, coalesced.

#define SC_ABUF 4096             // 128*32 elements per A buffer (8 KiB)

__global__ __launch_bounds__(512, 4)
void score_kernel_bl2(const __bf16* __restrict__ valb, const __bf16* __restrict__ W1TT,
                      const float* __restrict__ projq, const float* __restrict__ V,
                      float* __restrict__ score) {
    __shared__ __attribute__((aligned(16))) __bf16 lds[3 * SC_ABUF];  // 24 KiB

    const int tid  = threadIdx.x;
    const int bid  = blockIdx.x;
    const int xcd  = bid & 7;
    const int sl   = bid >> 3;            // 0..255
    const int mblk = xcd * 64 + (sl >> 2);  // 0..511 (128 rows each)
    const int nblk = sl & 3;                // 256 cols each

    const int wv   = tid >> 6;            // wave 0..7
    const int lane = tid & 63;
    const int wm   = wv >> 2;             // 0..1 : 64-row slice
    const int wn   = wv & 3;              // 0..3 : 64-col slice
    const int l15  = lane & 15, quad = lane >> 4;

    // A read-side swizzled slot (elems)
    const int rslot = (quad ^ ((l15 >> 1) & 3)) * 8;

    // A staging: lane covers row (wv*16 + lane>>2), phys slot (lane&3);
    // logical (pre-swizzled) source slot = (lane&3) ^ ((srow>>1)&3)
    const int srow = lane >> 2;           // 0..15
    const int slog = ((lane & 3) ^ ((srow >> 1) & 3)) * 8;
    const __bf16* aS = valb + ((size_t)mblk * 128 + wv * 16 + srow) * D_ + slog;
    __bf16* aD = lds + wv * 512;          // + buf offset

    // B fragment base: u-tile (nblk*16 + wn*4 + nt), lane slot (l15*4+quad)*8
    const __bf16* bB = W1TT + ((size_t)(nblk * 16 + wn * 4) * 32) * 512
                            + (l15 * 4 + quad) * 8;

#define DSR(dst, off) do { s16x8 _t;                                            \
    asm volatile("ds_read_b128 %0, %1" : "=v"(_t)                              \
        : "v"((const __attribute__((address_space(3))) __bf16*)(lds + (off)))); \
    (dst) = __builtin_bit_cast(bf16x8, _t); } while (0)

// Per step KT (buf CBR): B(t) loads FIRST, then glls16 A(t+2) -> CBS.
// Compiler's counted vmcnt for bf use retires older A(t+1), keeps A(t+2).
#define STEP(KT, CBR, CBS, DOS) do {                                            \
    bf16x8 bf[4];                                                               \
    _Pragma("unroll")                                                           \
    for (int nt = 0; nt < 4; ++nt)                                              \
        bf[nt] = *(const bf16x8*)(bB + ((size_t)(nt * 32 + (KT)) * 512));       \
    __builtin_amdgcn_sched_barrier(0);                                          \
    if (DOS) glls16(aS + ((KT) + 2) * 32, aD + (CBS));                          \
    bf16x8 af[4];                                                               \
    _Pragma("unroll")                                                           \
    for (int mt = 0; mt < 4; ++mt)                                              \
        DSR(af[mt], (CBR) + (wm * 64 + mt * 16 + l15) * 32 + rslot);            \
    asm volatile("s_waitcnt lgkmcnt(0)" ::: "memory");                          \
    __builtin_amdgcn_sched_barrier(0);                                          \
    __builtin_amdgcn_s_setprio(1);                                              \
    _Pragma("unroll")                                                           \
    for (int nt = 0; nt < 4; ++nt)                                              \
    _Pragma("unroll")                                                           \
    for (int mt = 0; mt < 4; ++mt)                                              \
        acc[mt][nt] = __builtin_amdgcn_mfma_f32_16x16x32_bf16(                  \
            af[mt], bf[nt], acc[mt][nt], 0, 0, 0);                              \
    __builtin_amdgcn_s_setprio(0);                                              \
    __builtin_amdgcn_s_barrier();                                               \
} while (0)

    f32x4 acc[4][4];
#pragma unroll
    for (int i = 0; i < 4; ++i)
#pragma unroll
        for (int j = 0; j < 4; ++j) { f32x4 z = {0.f, 0.f, 0.f, 0.f}; acc[i][j] = z; }

    // prologue: A(0)->buf0, A(1)->buf1; drain A(0), keep A(1) flying.
    glls16(aS + 0,  aD + 0);
    glls16(aS + 32, aD + SC_ABUF);
    asm volatile("s_waitcnt vmcnt(1)" ::: "memory");
    __builtin_amdgcn_s_barrier();

#pragma unroll 1
    for (int t = 0; t < 30; t += 3) {
        STEP(t,     0,           2 * SC_ABUF, 1);
        STEP(t + 1, SC_ABUF,     0,           1);
        STEP(t + 2, 2 * SC_ABUF, SC_ABUF,     1);
    }
    STEP(30, 0,       0, 0);
    STEP(31, SC_ABUF, 0, 0);

    // epilogue: partial score = sum_u tanh(acc + projq[b][u]) * V[u]
    const int bq = mblk >> 4;                  // 16 mblks (of 128 rows) per batch
    const float* pq = projq + (size_t)bq * U_ + nblk * 256 + wn * 64;
    const float* Vp = V + nblk * 256 + wn * 64;
    float pqu[4], vu[4];
#pragma unroll
    for (int nt = 0; nt < 4; ++nt) { pqu[nt] = pq[nt * 16 + l15]; vu[nt] = Vp[nt * 16 + l15]; }
    const size_t rowbase = (size_t)mblk * 128 + (size_t)wm * 64;
#pragma unroll
    for (int mt = 0; mt < 4; ++mt) {
        float s0 = 0.f, s1 = 0.f, s2 = 0.f, s3 = 0.f;
#pragma unroll
        for (int nt = 0; nt < 4; ++nt) {
            s0 += tanh_fast(acc[mt][nt][0] + pqu[nt]) * vu[nt];
            s1 += tanh_fast(acc[mt][nt][1] + pqu[nt]) * vu[nt];
            s2 += tanh_fast(acc[mt][nt][2] + pqu[nt]) * vu[nt];
            s3 += tanh_fast(acc[mt][nt][3] + pqu[nt]) * vu[nt];
        }
        float s[4] = {s0, s1, s2, s3};
#pragma unroll
        for (int r = 0; r < 4; ++r) {
            float v = s[r];
            v += __shfl_xor(v, 1);
            v += __shfl_xor(v, 2);
            v += __shfl_xor(v, 4);
            v += __shfl_xor(v, 8);
            if (l15 == 0)
                atomicAdd(&score[rowbase + mt * 16 + quad * 4 + r], v);
        }
    }
#undef DSR
#undef STEP
}

// ---------------- R1 fallback score GEMM (fp32 staging), if ws too small ----
__global__ __launch_bounds__(512, 2)
void score_kernel_f32(const float* __restrict__ values, const __bf16* __restrict__ W1T,
                      const float* __restrict__ projq, const float* __restrict__ V,
                      float* __restrict__ score) {
    __shared__ __attribute__((aligned(16))) __bf16 Al[64][40];
    __shared__ __attribute__((aligned(16))) __bf16 Bl[512][40];
    const int tid    = threadIdx.x;
    const int rowblk = blockIdx.x >> 1;
    const int nhalf  = blockIdx.x & 1;
    const int wave = tid >> 6, lane = tid & 63;
    const int quad = lane >> 4, l15 = lane & 15;
    const float*  Abase = values + (size_t)rowblk * 64 * D_;
    const __bf16* Bbase = W1T + (size_t)nhalf * 512 * D_;
    const int ar = tid >> 3, ac = (tid & 7) * 4;
    const int br = tid >> 2, bc = (tid & 3) * 8;
    f32x4 acc[4][4];
#pragma unroll
    for (int i = 0; i < 4; ++i)
#pragma unroll
        for (int j = 0; j < 4; ++j) { f32x4 z = {0.f,0.f,0.f,0.f}; acc[i][j] = z; }
    for (int kk = 0; kk < D_; kk += 32) {
        {
            const float4 v = *(const float4*)(Abase + (size_t)ar * D_ + kk + ac);
            bf16x4 h;
            h[0] = (__bf16)v.x; h[1] = (__bf16)v.y; h[2] = (__bf16)v.z; h[3] = (__bf16)v.w;
            *(bf16x4*)(&Al[ar][ac]) = h;
        }
#pragma unroll
        for (int p = 0; p < 4; ++p) {
            const int rr = p * 128 + br;
            const bf16x8 w = *(const bf16x8*)(Bbase + (size_t)rr * D_ + kk + bc);
            *(bf16x8*)(&Bl[rr][bc]) = w;
        }
        __syncthreads();
        bf16x8 af[4];
#pragma unroll
        for (int mt = 0; mt < 4; ++mt)
            af[mt] = *(const bf16x8*)(&Al[mt * 16 + l15][quad * 8]);
#pragma unroll
        for (int nt = 0; nt < 4; ++nt) {
            const bf16x8 bfr = *(const bf16x8*)(&Bl[wave * 64 + nt * 16 + l15][quad * 8]);
#pragma unroll
            for (int mt = 0; mt < 4; ++mt)
                acc[mt][nt] = __builtin_amdgcn_mfma_f32_16x16x32_bf16(af[mt], bfr, acc[mt][nt], 0, 0, 0);
        }
        __syncthreads();
    }
    const int b = rowblk >> 5;
    const size_t rowbase = (size_t)rowblk * 64;
    const float* pq = projq + (size_t)b * U_;
    const int ub = nhalf * 512 + wave * 64;
#pragma unroll
    for (int mt = 0; mt < 4; ++mt) {
        float s0 = 0.f, s1 = 0.f, s2 = 0.f, s3 = 0.f;
#pragma unroll
        for (int nt = 0; nt < 4; ++nt) {
            const int u = ub + nt * 16 + l15;
            const float pqu = pq[u];
            const float vu  = V[u];
            s0 += tanh_fast(acc[mt][nt][0] + pqu) * vu;
            s1 += tanh_fast(acc[mt][nt][1] + pqu) * vu;
            s2 += tanh_fast(acc[mt][nt][2] + pqu) * vu;
            s3 += tanh_fast(acc[mt][nt][3] + pqu) * vu;
        }
        float s[4] = {s0, s1, s2, s3};
#pragma unroll
        for (int r = 0; r < 4; ++r) {
            float v = s[r];
            v += __shfl_xor(v, 1);
            v += __shfl_xor(v, 2);
            v += __shfl_xor(v, 4);
            v += __shfl_xor(v, 8);
            if (l15 == 0)
                atomicAdd(&score[rowbase + mt * 16 + quad * 4 + r], v);
        }
    }
}

// ---------------- softmax over T (masked), writes attention weights ----------------
__global__ void softmax_kernel(const float* __restrict__ score, const float* __restrict__ mask,
                               const float* __restrict__ bV, float* __restrict__ out) {
    const int b = blockIdx.x;     // 32
    const int tid = threadIdx.x;  // 256
    const float bv = bV[0];
    float s[8];
    float lmax = -3.0e38f;
#pragma unroll
    for (int i = 0; i < 8; ++i) {
        const int t = tid + i * 256;
        const float v = score[(size_t)b * T_ + t] + bv + mask[(size_t)b * T_ + t] * (-1.0e9f);
        s[i] = v;
        lmax = fmaxf(lmax, v);
    }
#pragma unroll
    for (int m = 1; m < 64; m <<= 1) lmax = fmaxf(lmax, __shfl_xor(lmax, m));
    __shared__ float redm[4], reds[4];
    if ((tid & 63) == 0) redm[tid >> 6] = lmax;
    __syncthreads();
    const float M = fmaxf(fmaxf(redm[0], redm[1]), fmaxf(redm[2], redm[3]));
    float lsum = 0.f;
#pragma unroll
    for (int i = 0; i < 8; ++i) { s[i] = __expf(s[i] - M); lsum += s[i]; }
#pragma unroll
    for (int m = 1; m < 64; m <<= 1) lsum += __shfl_xor(lsum, m);
    if ((tid & 63) == 0) reds[tid >> 6] = lsum;
    __syncthreads();
    const float inv = 1.0f / (reds[0] + reds[1] + reds[2] + reds[3]);
#pragma unroll
    for (int i = 0; i < 8; ++i)
        out[(size_t)B_ * D_ + (size_t)b * T_ + tid + i * 256] = s[i] * inv;
}

// ---------------- context = sum_t attn[b,t] * valb[b,t,:]  (bf16 values) ----
__global__ void context_kernel_bf16(const __bf16* __restrict__ valb, const float* __restrict__ attn,
                                    float* __restrict__ out) {
    const int b  = blockIdx.x >> 4;   // 32
    const int dc = blockIdx.x & 15;   // 16 chunks of 64 d
    const int tid = threadIdx.x;      // 256
    __shared__ float a[T_];
#pragma unroll
    for (int i = 0; i < 8; ++i) a[tid + i * 256] = attn[(size_t)b * T_ + tid + i * 256];
    __syncthreads();
    const int dl = (tid & 7) * 8;     // 8 bf16 (16 B) per thread
    const int tg = tid >> 3;          // 0..31
    const __bf16* vb = valb + (size_t)b * T_ * D_ + dc * 64 + dl;
    float acc[8];
#pragma unroll
    for (int j = 0; j < 8; ++j) acc[j] = 0.f;
#pragma unroll 4
    for (int t = tg; t < T_; t += 32) {
        const bf16x8 v = *(const bf16x8*)(vb + (size_t)t * D_);
        const float w = a[t];
#pragma unroll
        for (int j = 0; j < 8; ++j) acc[j] = fmaf(w, (float)v[j], acc[j]);
    }
    __shared__ __attribute__((aligned(16))) float red[32][65];
#pragma unroll
    for (int j = 0; j < 8; ++j) red[tg][dl + j] = acc[j];
    __syncthreads();
    if (tid < 64) {
        float s = 0.f;
#pragma unroll
        for (int g = 0; g < 32; ++g) s += red[g][tid];
        out[(size_t)b * D_ + dc * 64 + tid] = s;
    }
}

// ---------------- fallback context (fp32 values) ----------------
__global__ void context_kernel(const float* __restrict__ values, const float* __restrict__ attn,
                               float* __restrict__ out) {
    const int b  = blockIdx.x >> 4;   // 32
    const int dc = blockIdx.x & 15;   // 16 chunks of 64 d
    const int tid = threadIdx.x;      // 256
    __shared__ float a[T_];
#pragma unroll
    for (int i = 0; i < 8; ++i) a[tid + i * 256] = attn[(size_t)b * T_ + tid + i * 256];
    __syncthreads();
    const int dl = (tid & 15) * 4;    // 64 d per block, float4 per thread
    const int tg = tid >> 4;          // 0..15
    const float* vb = values + (size_t)b * T_ * D_ + dc * 64 + dl;
    f32x4 acc = {0.f, 0.f, 0.f, 0.f};
#pragma unroll 4
    for (int t = tg; t < T_; t += 16) {
        const float4 v = *(const float4*)(vb + (size_t)t * D_);
        const float w = a[t];
        acc[0] = fmaf(w, v.x, acc[0]);
        acc[1] = fmaf(w, v.y, acc[1]);
        acc[2] = fmaf(w, v.z, acc[2]);
        acc[3] = fmaf(w, v.w, acc[3]);
    }
    __shared__ __attribute__((aligned(16))) float red[16][64];
    *(f32x4*)(&red[tg][dl]) = acc;
    __syncthreads();
    if (tid < 64) {
        float s = 0.f;
#pragma unroll
        for (int g = 0; g < 16; ++g) s += red[g][tid];
        out[(size_t)b * D_ + dc * 64 + tid] = s;
    }
}

extern "C" void kernel_launch(void* const* d_in, const int* in_sizes, int n_in,
                              void* d_out, int out_size, void* d_ws, size_t ws_size,
                              hipStream_t stream) {
    const float* values = (const float*)d_in[0];
    const float* query  = (const float*)d_in[1];
    const float* mask   = (const float*)d_in[2];
    const float* W1     = (const float*)d_in[3];
    const float* b1     = (const float*)d_in[4];
    const float* W2     = (const float*)d_in[5];
    const float* b2     = (const float*)d_in[6];
    const float* V      = (const float*)d_in[7];
    const float* bV     = (const float*)d_in[8];
    float* out = (float*)d_out;

    char* ws = (char*)d_ws;
    __bf16* W1T   = (__bf16*)(ws + WS_W1T);   // tiled (main) or row (fallback)
    float*  projq = (float*)(ws + WS_PROJQ);
    float*  score = (float*)(ws + WS_SCORE);
    __bf16* valb  = (__bf16*)(ws + WS_VALB);

    init_kernel<<<dim3(384), dim3(256), 0, stream>>>(b1, b2, projq, score);
    projq_kernel<<<dim3(256), dim3(256), 0, stream>>>(query, W2, projq);
    if (ws_size >= WS_NEEDED) {
        w1_transpose_tiled_kernel<<<dim3(256), dim3(256), 0, stream>>>(W1, W1T);
        convert_kernel<<<dim3(32768), dim3(256), 0, stream>>>(values, valb);
        score_kernel_bl2<<<dim3(2048), dim3(512), 0, stream>>>(valb, W1T, projq, V, score);
        softmax_kernel<<<dim3(32), dim3(256), 0, stream>>>(score, mask, bV, out);
        context_kernel_bf16<<<dim3(512), dim3(256), 0, stream>>>(valb, out + B_ * D_, out);
    } else {
        w1_transpose_kernel<<<dim3(256), dim3(256), 0, stream>>>(W1, W1T);
        score_kernel_f32<<<dim3(2048), dim3(512), 0, stream>>>(values, W1T, projq, V, score);
        softmax_kernel<<<dim3(32), dim3(256), 0, stream>>>(score, mask, bV, out);
        context_kernel<<<dim3(512), dim3(256), 0, stream>>>(values, out + B_ * D_, out);
    }
}